// Round 1
// baseline (139.818 us; speedup 1.0000x reference)
//
#include <hip/hip_runtime.h>

typedef __attribute__((ext_vector_type(8))) short short8;
typedef __attribute__((ext_vector_type(4))) float f32x4;

static __device__ __forceinline__ short f2bf(float f) {
  union { float f; unsigned u; } v; v.f = f;
  unsigned r = (v.u + 0x7FFFu + ((v.u >> 16) & 1u)) >> 16;   // RNE
  return (short)r;
}

// ---- x fp32 -> bf16, 8 elems/thread ----
__global__ __launch_bounds__(256) void k_cvt_x(const float* __restrict__ x,
                                               short* __restrict__ xb, int n8) {
  int i = blockIdx.x * 256 + threadIdx.x;
  if (i >= n8) return;
  const f32x4* s = (const f32x4*)x + (size_t)i * 2;
  f32x4 a = s[0], b = s[1];
  short8 o;
  o[0] = f2bf(a[0]); o[1] = f2bf(a[1]); o[2] = f2bf(a[2]); o[3] = f2bf(a[3]);
  o[4] = f2bf(b[0]); o[5] = f2bf(b[1]); o[6] = f2bf(b[2]); o[7] = f2bf(b[3]);
  ((short8*)xb)[i] = o;
}

// ---- w1 = bf16(k0*m0*scale), 8 elems/thread ----
__global__ __launch_bounds__(256) void k_maskmul(const float* __restrict__ k,
                                                 const float* __restrict__ m,
                                                 const float* __restrict__ scale,
                                                 short* __restrict__ out, int n8) {
  int i = blockIdx.x * 256 + threadIdx.x;
  if (i >= n8) return;
  float s = scale[0];
  const f32x4* kk = (const f32x4*)k + (size_t)i * 2;
  const f32x4* mm = (const f32x4*)m + (size_t)i * 2;
  f32x4 a0 = kk[0], a1 = kk[1], b0 = mm[0], b1 = mm[1];
  short8 o;
  o[0] = f2bf(a0[0] * b0[0] * s); o[1] = f2bf(a0[1] * b0[1] * s);
  o[2] = f2bf(a0[2] * b0[2] * s); o[3] = f2bf(a0[3] * b0[3] * s);
  o[4] = f2bf(a1[0] * b1[0] * s); o[5] = f2bf(a1[1] * b1[1] * s);
  o[6] = f2bf(a1[2] * b1[2] * s); o[7] = f2bf(a1[3] * b1[3] * s);
  ((short8*)out)[i] = o;
}

// ---- out[f][d] = bf16(in[d][f] * m[d][f]) : masked transpose, 32x32 LDS tiles ----
__global__ __launch_bounds__(256) void k_tmask(const float* __restrict__ k,
                                               const float* __restrict__ m,
                                               short* __restrict__ out, int D, int F) {
  __shared__ float tile[32][33];
  int f0 = blockIdx.x * 32, d0 = blockIdx.y * 32;
  int tx = threadIdx.x, ty = threadIdx.y;  // (32,8)
#pragma unroll
  for (int i = 0; i < 4; ++i) {
    int d = d0 + ty + i * 8;
    size_t idx = (size_t)d * F + f0 + tx;
    tile[ty + i * 8][tx] = k[idx] * m[idx];
  }
  __syncthreads();
#pragma unroll
  for (int i = 0; i < 4; ++i) {
    int f = f0 + ty + i * 8;
    out[(size_t)f * D + d0 + tx] = f2bf(tile[tx][ty + i * 8]);
  }
}

// ---- generic bf16 GEMM: C[M][N] = A[M][K] @ BT[N][K]^T, 128x128x64 tiles ----
__global__ __launch_bounds__(256) void k_gemm(const short* __restrict__ A,
                                              const short* __restrict__ BT,
                                              short* __restrict__ C, int M, int N, int K) {
  __shared__ __align__(16) short As[128][64];
  __shared__ __align__(16) short Bs[128][64];
  const int ntiles = N >> 7;
  const int mt = blockIdx.x / ntiles, nt = blockIdx.x % ntiles;
  const int m0 = mt << 7, n0 = nt << 7;
  const int tid = threadIdx.x;
  const int lane = tid & 63, wv = tid >> 6;
  const int wr = (wv >> 1) * 64, wc = (wv & 1) * 64;
  const int lr = lane & 15, lk = (lane >> 4) * 8;

  f32x4 acc[4][4] = {};

  const int r = tid >> 1, half = (tid & 1) * 32;
  const short* aSrc = A + (size_t)(m0 + r) * K + half;
  const short* bSrc = BT + (size_t)(n0 + r) * K + half;

  for (int kt = 0; kt < K; kt += 64) {
    short8* ad = (short8*)&As[r][half];
    short8* bd = (short8*)&Bs[r][half];
    const short8* as = (const short8*)(aSrc + kt);
    const short8* bs = (const short8*)(bSrc + kt);
#pragma unroll
    for (int j = 0; j < 4; ++j) ad[j] = as[j];
#pragma unroll
    for (int j = 0; j < 4; ++j) bd[j] = bs[j];
    __syncthreads();
#pragma unroll
    for (int ks = 0; ks < 2; ++ks) {
      const int ko = ks * 32 + lk;
      short8 af[4], bf[4];
#pragma unroll
      for (int i = 0; i < 4; ++i) af[i] = *(const short8*)&As[wr + i * 16 + lr][ko];
#pragma unroll
      for (int i = 0; i < 4; ++i) bf[i] = *(const short8*)&Bs[wc + i * 16 + lr][ko];
#pragma unroll
      for (int mi = 0; mi < 4; ++mi)
#pragma unroll
        for (int ni = 0; ni < 4; ++ni)
          acc[mi][ni] = __builtin_amdgcn_mfma_f32_16x16x32_bf16(af[mi], bf[ni], acc[mi][ni], 0, 0, 0);
    }
    __syncthreads();
  }
#pragma unroll
  for (int mi = 0; mi < 4; ++mi) {
    const int row = m0 + wr + mi * 16 + (lane >> 4) * 4;
#pragma unroll
    for (int ni = 0; ni < 4; ++ni) {
      const int col = n0 + wc + ni * 16 + lr;
#pragma unroll
      for (int q = 0; q < 4; ++q)
        C[(size_t)(row + q) * N + col] = f2bf(acc[mi][ni][q]);
    }
  }
}

// ---- conv as implicit-im2col GEMM: out[32768][512] = im2col(xb)[32768][1152] @ wT[512][1152]^T + bias
__global__ __launch_bounds__(256) void k_conv(const short* __restrict__ xb,
                                              const short* __restrict__ wT,
                                              const float* __restrict__ bias,
                                              float* __restrict__ out) {
  __shared__ __align__(16) short As[128][64];
  __shared__ __align__(16) short Bs[128][64];
  int bid = blockIdx.x;
  bid = (bid & 7) * 128 + (bid >> 3);  // bijective XCD swizzle (1024 % 8 == 0)
  const int mt = bid >> 2, nt = bid & 3;
  const int m0 = mt << 7, n0 = nt << 7;
  const int tid = threadIdx.x;
  const int lane = tid & 63, wv = tid >> 6;
  const int wr = (wv >> 1) * 64, wc = (wv & 1) * 64;
  const int lr = lane & 15, lk = (lane >> 4) * 8;

  f32x4 acc[4][4] = {};

  const int r = tid >> 1, half = (tid & 1) * 32;
  const int m = m0 + r;
  const int b = m >> 10, h = (m >> 5) & 31, w = m & 31;
  const short* bSrc = wT + (size_t)(n0 + r) * 1152 + half;

  for (int kt = 0; kt < 18; ++kt) {
    const int kg = kt << 6;
    const int khw = kg >> 7;   // (kh*3+kw), 0..8
    const int c0 = kg & 127;   // 0 or 64
    const int kh = (khw >= 6) ? 2 : (khw >= 3 ? 1 : 0);
    const int kw = khw - kh * 3;
    const int hs = h + kh - 1, ws2 = w + kw - 1;
    const bool valid = ((unsigned)hs < 32u) && ((unsigned)ws2 < 32u);
    short8* ad = (short8*)&As[r][half];
    if (valid) {
      const short8* as = (const short8*)(xb + ((((size_t)(b << 5) + hs) << 5) + ws2) * 128 + c0 + half);
#pragma unroll
      for (int j = 0; j < 4; ++j) ad[j] = as[j];
    } else {
      short8 z = {};
#pragma unroll
      for (int j = 0; j < 4; ++j) ad[j] = z;
    }
    short8* bd = (short8*)&Bs[r][half];
    const short8* bs = (const short8*)(bSrc + kg);
#pragma unroll
    for (int j = 0; j < 4; ++j) bd[j] = bs[j];
    __syncthreads();
#pragma unroll
    for (int ks = 0; ks < 2; ++ks) {
      const int ko = ks * 32 + lk;
      short8 af[4], bf[4];
#pragma unroll
      for (int i = 0; i < 4; ++i) af[i] = *(const short8*)&As[wr + i * 16 + lr][ko];
#pragma unroll
      for (int i = 0; i < 4; ++i) bf[i] = *(const short8*)&Bs[wc + i * 16 + lr][ko];
#pragma unroll
      for (int mi = 0; mi < 4; ++mi)
#pragma unroll
        for (int ni = 0; ni < 4; ++ni)
          acc[mi][ni] = __builtin_amdgcn_mfma_f32_16x16x32_bf16(af[mi], bf[ni], acc[mi][ni], 0, 0, 0);
    }
    __syncthreads();
  }
#pragma unroll
  for (int mi = 0; mi < 4; ++mi) {
    const int row = m0 + wr + mi * 16 + (lane >> 4) * 4;
#pragma unroll
    for (int ni = 0; ni < 4; ++ni) {
      const int col = n0 + wc + ni * 16 + lr;
      const float bv = bias[col];
#pragma unroll
      for (int q = 0; q < 4; ++q)
        out[(size_t)(row + q) * 512 + col] = acc[mi][ni][q] + bv;
    }
  }
}

extern "C" void kernel_launch(void* const* d_in, const int* in_sizes, int n_in,
                              void* d_out, int out_size, void* d_ws, size_t ws_size,
                              hipStream_t stream) {
  (void)in_sizes; (void)n_in; (void)out_size; (void)ws_size;
  const float* x    = (const float*)d_in[0];
  const float* k0   = (const float*)d_in[1];
  const float* k1   = (const float*)d_in[2];
  const float* k2   = (const float*)d_in[3];
  const float* m0   = (const float*)d_in[4];
  const float* m1   = (const float*)d_in[5];
  const float* m2   = (const float*)d_in[6];
  const float* sc   = (const float*)d_in[7];
  const float* bias = (const float*)d_in[8];
  float* out = (float*)d_out;
  char* ws = (char*)d_ws;

  short* xb  = (short*)(ws);             // 32*32*32*128 bf16  = 8,388,608 B
  short* w1b = (short*)(ws + 8388608);   // 1152*1152 bf16     = 2,654,208 B
  short* w2T = (short*)(ws + 11042816);  // 512*1152 bf16      = 1,179,648 B
  short* w3T = (short*)(ws + 12222464);  // 512*512 bf16       =   524,288 B
  short* A1b = (short*)(ws + 12746752);  // 1152*512 bf16      = 1,179,648 B
  short* wET = (short*)(ws + 13926400);  // 512*1152 bf16      = 1,179,648 B

  k_cvt_x<<<2048, 256, 0, stream>>>(x, xb, 524288);
  k_maskmul<<<648, 256, 0, stream>>>(k0, m0, sc, w1b, 165888);
  k_tmask<<<dim3(16, 36), dim3(32, 8), 0, stream>>>(k1, m1, w2T, 1152, 512);
  k_tmask<<<dim3(16, 16), dim3(32, 8), 0, stream>>>(k2, m2, w3T, 512, 512);
  // A1 (1152x512) = w1 @ w2 ;  A=w1b[1152][1152], BT=w2T[512][1152]
  k_gemm<<<36, 256, 0, stream>>>(w1b, w2T, A1b, 1152, 512, 1152);
  // wEffT (512x1152) = w3T @ A1^T  (== (A1@w3)^T) ; A=w3T[512][512], BT=A1b[1152][512]
  k_gemm<<<36, 256, 0, stream>>>(w3T, A1b, wET, 512, 1152, 512);
  k_conv<<<1024, 256, 0, stream>>>(xb, wET, bias, out);
}

// Round 2
// 103.777 us; speedup vs baseline: 1.3473x; 1.3473x over previous
//
#include <hip/hip_runtime.h>

typedef __attribute__((ext_vector_type(8))) short short8;
typedef __attribute__((ext_vector_type(4))) float f32x4;

typedef __attribute__((address_space(1))) const unsigned gas_u32;
typedef __attribute__((address_space(3))) unsigned las_u32;

// async global->LDS, 16B per lane; lds ptr must be wave-uniform (dest = base + lane*16)
static __device__ __forceinline__ void g2l16(const void* g, void* l) {
  __builtin_amdgcn_global_load_lds((gas_u32*)g, (las_u32*)l, 16, 0, 0);
}

static __device__ __forceinline__ short f2bf(float f) {
  union { float f; unsigned u; } v; v.f = f;
  unsigned r = (v.u + 0x7FFFu + ((v.u >> 16) & 1u)) >> 16;   // RNE
  return (short)r;
}

// ---- x fp32 -> bf16 into zero-padded xbp[32][34][34][128]; 8 elems/thread ----
__global__ __launch_bounds__(256) void k_cvt_pad(const float* __restrict__ x,
                                                 short* __restrict__ xbp, int n8) {
  int i = blockIdx.x * 256 + threadIdx.x;
  if (i >= n8) return;
  int c8 = i & 15;              // which 8-channel group
  int t = i >> 4;               // (b*34 + hp)*34 + wp
  int wp = t % 34, t2 = t / 34;
  int hp = t2 % 34, b = t2 / 34;
  short8 o = {};
  if (hp >= 1 && hp <= 32 && wp >= 1 && wp <= 32) {
    const f32x4* s = (const f32x4*)(x + (((size_t)((b << 5) + hp - 1) << 5) + (wp - 1)) * 128 + c8 * 8);
    f32x4 a = s[0], bb = s[1];
    o[0] = f2bf(a[0]); o[1] = f2bf(a[1]); o[2] = f2bf(a[2]); o[3] = f2bf(a[3]);
    o[4] = f2bf(bb[0]); o[5] = f2bf(bb[1]); o[6] = f2bf(bb[2]); o[7] = f2bf(bb[3]);
  }
  ((short8*)xbp)[i] = o;
}

// ---- w1 = bf16(k0*m0*scale), 8 elems/thread ----
__global__ __launch_bounds__(256) void k_maskmul(const float* __restrict__ k,
                                                 const float* __restrict__ m,
                                                 const float* __restrict__ scale,
                                                 short* __restrict__ out, int n8) {
  int i = blockIdx.x * 256 + threadIdx.x;
  if (i >= n8) return;
  float s = scale[0];
  const f32x4* kk = (const f32x4*)k + (size_t)i * 2;
  const f32x4* mm = (const f32x4*)m + (size_t)i * 2;
  f32x4 a0 = kk[0], a1 = kk[1], b0 = mm[0], b1 = mm[1];
  short8 o;
  o[0] = f2bf(a0[0] * b0[0] * s); o[1] = f2bf(a0[1] * b0[1] * s);
  o[2] = f2bf(a0[2] * b0[2] * s); o[3] = f2bf(a0[3] * b0[3] * s);
  o[4] = f2bf(a1[0] * b1[0] * s); o[5] = f2bf(a1[1] * b1[1] * s);
  o[6] = f2bf(a1[2] * b1[2] * s); o[7] = f2bf(a1[3] * b1[3] * s);
  ((short8*)out)[i] = o;
}

// ---- out[f][d] = bf16(in[d][f] * m[d][f]) : masked transpose, 32x32 LDS tiles ----
__global__ __launch_bounds__(256) void k_tmask(const float* __restrict__ k,
                                               const float* __restrict__ m,
                                               short* __restrict__ out, int D, int F) {
  __shared__ float tile[32][33];
  int f0 = blockIdx.x * 32, d0 = blockIdx.y * 32;
  int tx = threadIdx.x, ty = threadIdx.y;  // (32,8)
#pragma unroll
  for (int i = 0; i < 4; ++i) {
    int d = d0 + ty + i * 8;
    size_t idx = (size_t)d * F + f0 + tx;
    tile[ty + i * 8][tx] = k[idx] * m[idx];
  }
  __syncthreads();
#pragma unroll
  for (int i = 0; i < 4; ++i) {
    int f = f0 + ty + i * 8;
    out[(size_t)f * D + d0 + tx] = f2bf(tile[tx][ty + i * 8]);
  }
}

// ---- bf16 GEMM 64x64 tiles: C[M][N] = A[M][K] @ BT[N][K]^T  (gload_lds staging) ----
__global__ __launch_bounds__(256) void k_gemm64(const short* __restrict__ A,
                                                const short* __restrict__ BT,
                                                short* __restrict__ C, int M, int N, int K) {
  __shared__ __align__(16) short As[64][64];
  __shared__ __align__(16) short Bs[64][64];
  const int ntiles = N >> 6;
  const int m0 = (blockIdx.x / ntiles) << 6, n0 = (blockIdx.x % ntiles) << 6;
  const int tid = threadIdx.x;
  const int lane = tid & 63, wv = tid >> 6;
  const int wr = (wv >> 1) * 32, wc = (wv & 1) * 32;
  const int lr = lane & 15, lk = (lane >> 4) * 8;

  f32x4 acc[2][2] = {};

  const int rr = tid >> 3, c8 = (tid & 7) * 8;
  unsigned abase[2], bbase[2];
#pragma unroll
  for (int j = 0; j < 2; ++j) {
    abase[j] = (unsigned)(m0 + j * 32 + rr) * K + c8;
    bbase[j] = (unsigned)(n0 + j * 32 + rr) * K + c8;
  }
  short* AsL = &As[0][0];
  short* BsL = &Bs[0][0];
  const int lo = wv * 512;  // shorts; wave-uniform

  for (int kt = 0; kt < K; kt += 64) {
#pragma unroll
    for (int j = 0; j < 2; ++j) g2l16(A + abase[j] + kt, AsL + j * 2048 + lo);
#pragma unroll
    for (int j = 0; j < 2; ++j) g2l16(BT + bbase[j] + kt, BsL + j * 2048 + lo);
    __syncthreads();
#pragma unroll
    for (int ks = 0; ks < 2; ++ks) {
      const int ko = ks * 32 + lk;
      short8 af[2], bf[2];
#pragma unroll
      for (int i = 0; i < 2; ++i) af[i] = *(const short8*)&As[wr + i * 16 + lr][ko];
#pragma unroll
      for (int i = 0; i < 2; ++i) bf[i] = *(const short8*)&Bs[wc + i * 16 + lr][ko];
#pragma unroll
      for (int mi = 0; mi < 2; ++mi)
#pragma unroll
        for (int ni = 0; ni < 2; ++ni)
          acc[mi][ni] = __builtin_amdgcn_mfma_f32_16x16x32_bf16(af[mi], bf[ni], acc[mi][ni], 0, 0, 0);
    }
    __syncthreads();
  }
#pragma unroll
  for (int mi = 0; mi < 2; ++mi) {
    const int row = m0 + wr + mi * 16 + (lane >> 4) * 4;
#pragma unroll
    for (int ni = 0; ni < 2; ++ni) {
      const int col = n0 + wc + ni * 16 + lr;
#pragma unroll
      for (int q = 0; q < 4; ++q)
        C[(size_t)(row + q) * N + col] = f2bf(acc[mi][ni][q]);
    }
  }
}

// ---- conv as implicit-im2col GEMM with gload_lds staging ----
// out[32768][512] = im2col(xbp)[32768][1152] @ wT[512][1152]^T + bias
__global__ __launch_bounds__(256) void k_conv(const short* __restrict__ xbp,
                                              const short* __restrict__ wT,
                                              const float* __restrict__ bias,
                                              float* __restrict__ out) {
  __shared__ __align__(16) short As[128][64];
  __shared__ __align__(16) short Bs[128][64];
  int bid = blockIdx.x;
  bid = (bid & 7) * 128 + (bid >> 3);  // bijective XCD swizzle (1024 % 8 == 0)
  const int mt = bid >> 2, nt = bid & 3;
  const int m0 = mt << 7, n0 = nt << 7;
  const int tid = threadIdx.x;
  const int lane = tid & 63, wv = tid >> 6;
  const int wr = (wv >> 1) * 64, wc = (wv & 1) * 64;
  const int lr = lane & 15, lk = (lane >> 4) * 8;

  f32x4 acc[4][4] = {};

  // staging geometry: issue j=0..3, LDS row r = j*32 + tid/8, col8 = (tid&7)*8
  const int rr = tid >> 3, c8 = (tid & 7) * 8;
  unsigned abase[4], bbase[4];
#pragma unroll
  for (int j = 0; j < 4; ++j) {
    const int m = m0 + j * 32 + rr;
    const int b = m >> 10, h = (m >> 5) & 31, w = m & 31;
    abase[j] = (unsigned)((b * 34 + h) * 34 + w) * 128 + c8;  // padded coords: +kh,+kw gives h-1+kh
    bbase[j] = (unsigned)(n0 + j * 32 + rr) * 1152 + c8;
  }
  short* AsL = &As[0][0];
  short* BsL = &Bs[0][0];
  const int lo = wv * 512;  // shorts; wave-uniform

  for (int kt = 0; kt < 18; ++kt) {
    const int kg = kt << 6;
    const int khw = kg >> 7;        // kh*3+kw, 0..8
    const int c0 = kg & 127;        // 0 or 64
    const int kh = (khw * 11) >> 5; // khw/3
    const int kw = khw - kh * 3;
    const int aoff = (kh * 34 + kw) * 128 + c0;  // wave-uniform scalar
#pragma unroll
    for (int j = 0; j < 4; ++j) g2l16(xbp + abase[j] + aoff, AsL + j * 2048 + lo);
#pragma unroll
    for (int j = 0; j < 4; ++j) g2l16(wT + bbase[j] + kg, BsL + j * 2048 + lo);
    __syncthreads();
#pragma unroll
    for (int ks = 0; ks < 2; ++ks) {
      const int ko = ks * 32 + lk;
      short8 af[4], bf[4];
#pragma unroll
      for (int i = 0; i < 4; ++i) af[i] = *(const short8*)&As[wr + i * 16 + lr][ko];
#pragma unroll
      for (int i = 0; i < 4; ++i) bf[i] = *(const short8*)&Bs[wc + i * 16 + lr][ko];
#pragma unroll
      for (int mi = 0; mi < 4; ++mi)
#pragma unroll
        for (int ni = 0; ni < 4; ++ni)
          acc[mi][ni] = __builtin_amdgcn_mfma_f32_16x16x32_bf16(af[mi], bf[ni], acc[mi][ni], 0, 0, 0);
    }
    __syncthreads();
  }
#pragma unroll
  for (int mi = 0; mi < 4; ++mi) {
    const int row = m0 + wr + mi * 16 + (lane >> 4) * 4;
#pragma unroll
    for (int ni = 0; ni < 4; ++ni) {
      const int col = n0 + wc + ni * 16 + lr;
      const float bv = bias[col];
#pragma unroll
      for (int q = 0; q < 4; ++q)
        out[(size_t)(row + q) * 512 + col] = acc[mi][ni][q] + bv;
    }
  }
}

extern "C" void kernel_launch(void* const* d_in, const int* in_sizes, int n_in,
                              void* d_out, int out_size, void* d_ws, size_t ws_size,
                              hipStream_t stream) {
  (void)in_sizes; (void)n_in; (void)out_size; (void)ws_size;
  const float* x    = (const float*)d_in[0];
  const float* k0   = (const float*)d_in[1];
  const float* k1   = (const float*)d_in[2];
  const float* k2   = (const float*)d_in[3];
  const float* m0   = (const float*)d_in[4];
  const float* m1   = (const float*)d_in[5];
  const float* m2   = (const float*)d_in[6];
  const float* sc   = (const float*)d_in[7];
  const float* bias = (const float*)d_in[8];
  float* out = (float*)d_out;
  char* ws = (char*)d_ws;

  short* xbp = (short*)(ws);              // 32*34*34*128 bf16 = 9,469,952 B
  short* w1b = (short*)(ws + 9469952);    // 1152*1152 bf16    = 2,654,208 B
  short* w2T = (short*)(ws + 12124160);   // 512*1152 bf16     = 1,179,648 B
  short* w3T = (short*)(ws + 13303808);   // 512*512 bf16      =   524,288 B
  short* A1b = (short*)(ws + 13828096);   // 1152*512 bf16     = 1,179,648 B
  short* wET = (short*)(ws + 15007744);   // 512*1152 bf16     = 1,179,648 B

  k_cvt_pad<<<2312, 256, 0, stream>>>(x, xbp, 591872);       // 32*34*34*16
  k_maskmul<<<648, 256, 0, stream>>>(k0, m0, sc, w1b, 165888);
  k_tmask<<<dim3(16, 36), dim3(32, 8), 0, stream>>>(k1, m1, w2T, 1152, 512);
  k_tmask<<<dim3(16, 16), dim3(32, 8), 0, stream>>>(k2, m2, w3T, 512, 512);
  // A1 (1152x512) = w1 @ w2 ; A=w1b[1152][1152], BT=w2T[512][1152]
  k_gemm64<<<144, 256, 0, stream>>>(w1b, w2T, A1b, 1152, 512, 1152);
  // wEffT (512x1152) = w3T @ A1^T (== (A1@w3)^T) ; A=w3T[512][512], BT=A1b[1152][512]
  k_gemm64<<<144, 256, 0, stream>>>(w3T, A1b, wET, 512, 1152, 512);
  k_conv<<<1024, 256, 0, stream>>>(xbp, wET, bias, out);
}

// Round 4
// 79.413 us; speedup vs baseline: 1.7606x; 1.3068x over previous
//
#include <hip/hip_runtime.h>

typedef __attribute__((ext_vector_type(8))) short short8;
typedef __attribute__((ext_vector_type(4))) float f32x4;

typedef __attribute__((address_space(1))) const unsigned gas_u32;
typedef __attribute__((address_space(3))) unsigned las_u32;

static __device__ __forceinline__ void g2l16(const void* g, void* l) {
  __builtin_amdgcn_global_load_lds((gas_u32*)g, (las_u32*)l, 16, 0, 0);
}

static __device__ __forceinline__ short f2bf(float f) {
  union { float f; unsigned u; } v; v.f = f;
  unsigned r = (v.u + 0x7FFFu + ((v.u >> 16) & 1u)) >> 16;   // RNE
  return (short)r;
}

// ---- fused prep: maskmul | tmask(k1,m1) | tmask(k2,m2) | cvt_pad ----
__global__ __launch_bounds__(256) void k_prep(const float* __restrict__ x,
                                              const float* __restrict__ k0f,
                                              const float* __restrict__ m0f,
                                              const float* __restrict__ scf,
                                              const float* __restrict__ k1f,
                                              const float* __restrict__ m1f,
                                              const float* __restrict__ k2f,
                                              const float* __restrict__ m2f,
                                              short* __restrict__ xbp,
                                              short* __restrict__ w1b,
                                              short* __restrict__ w2T,
                                              short* __restrict__ w3T) {
  __shared__ float tile[32][33];
  const int bb = blockIdx.x, tid = threadIdx.x;
  if (bb < 648) {
    int i = bb * 256 + tid;
    float s = scf[0];
    const f32x4* kk = (const f32x4*)k0f + (size_t)i * 2;
    const f32x4* mm = (const f32x4*)m0f + (size_t)i * 2;
    f32x4 a0 = kk[0], a1 = kk[1], b0 = mm[0], b1 = mm[1];
    short8 o;
    o[0] = f2bf(a0[0] * b0[0] * s); o[1] = f2bf(a0[1] * b0[1] * s);
    o[2] = f2bf(a0[2] * b0[2] * s); o[3] = f2bf(a0[3] * b0[3] * s);
    o[4] = f2bf(a1[0] * b1[0] * s); o[5] = f2bf(a1[1] * b1[1] * s);
    o[6] = f2bf(a1[2] * b1[2] * s); o[7] = f2bf(a1[3] * b1[3] * s);
    ((short8*)w1b)[i] = o;
  } else if (bb < 1480) {
    const float *kf, *mf; short* outp; int D, F, idx;
    if (bb < 1224) { kf = k1f; mf = m1f; outp = w2T; D = 1152; F = 512; idx = bb - 648; }
    else           { kf = k2f; mf = m2f; outp = w3T; D = 512;  F = 512; idx = bb - 1224; }
    int f0 = (idx & 15) * 32, d0 = (idx >> 4) * 32;
    int tx = tid & 31, ty = tid >> 5;
#pragma unroll
    for (int i = 0; i < 4; ++i) {
      int d = d0 + ty + i * 8;
      size_t ix = (size_t)d * F + f0 + tx;
      tile[ty + i * 8][tx] = kf[ix] * mf[ix];
    }
    __syncthreads();
#pragma unroll
    for (int i = 0; i < 4; ++i) {
      int f = f0 + ty + i * 8;
      outp[(size_t)f * D + d0 + tx] = f2bf(tile[tx][ty + i * 8]);
    }
  } else {
    int i = (bb - 1480) * 256 + tid;
    int c8 = i & 15;
    int t = i >> 4;
    int wp = t % 34, t2 = t / 34;
    int hp = t2 % 34, b = t2 / 34;
    short8 o = {};
    if (hp >= 1 && hp <= 32 && wp >= 1 && wp <= 32) {
      const f32x4* s = (const f32x4*)(x + (((size_t)((b << 5) + hp - 1) << 5) + (wp - 1)) * 128 + c8 * 8);
      f32x4 a = s[0], bb2 = s[1];
      o[0] = f2bf(a[0]); o[1] = f2bf(a[1]); o[2] = f2bf(a[2]); o[3] = f2bf(a[3]);
      o[4] = f2bf(bb2[0]); o[5] = f2bf(bb2[1]); o[6] = f2bf(bb2[2]); o[7] = f2bf(bb2[3]);
    }
    ((short8*)xbp)[i] = o;
  }
}

// ---- bf16 GEMM 64x64 tiles: C[M][N] = A[M][K] @ BT[N][K]^T  (gload_lds staging) ----
__global__ __launch_bounds__(256) void k_gemm64(const short* __restrict__ A,
                                                const short* __restrict__ BT,
                                                short* __restrict__ C, int M, int N, int K) {
  __shared__ __align__(16) short As[64][64];
  __shared__ __align__(16) short Bs[64][64];
  const int ntiles = N >> 6;
  const int m0 = (blockIdx.x / ntiles) << 6, n0 = (blockIdx.x % ntiles) << 6;
  const int tid = threadIdx.x;
  const int lane = tid & 63, wv = tid >> 6;
  const int wr = (wv >> 1) * 32, wc = (wv & 1) * 32;
  const int lr = lane & 15, lk = (lane >> 4) * 8;

  f32x4 acc[2][2] = {};

  const int rr = tid >> 3, c8 = (tid & 7) * 8;
  unsigned abase[2], bbase[2];
#pragma unroll
  for (int j = 0; j < 2; ++j) {
    abase[j] = (unsigned)(m0 + j * 32 + rr) * K + c8;
    bbase[j] = (unsigned)(n0 + j * 32 + rr) * K + c8;
  }
  short* AsL = &As[0][0];
  short* BsL = &Bs[0][0];
  const int lo = wv * 512;

  for (int kt = 0; kt < K; kt += 64) {
#pragma unroll
    for (int j = 0; j < 2; ++j) g2l16(A + abase[j] + kt, AsL + j * 2048 + lo);
#pragma unroll
    for (int j = 0; j < 2; ++j) g2l16(BT + bbase[j] + kt, BsL + j * 2048 + lo);
    __syncthreads();
#pragma unroll
    for (int ks = 0; ks < 2; ++ks) {
      const int ko = ks * 32 + lk;
      short8 af[2], bf[2];
#pragma unroll
      for (int i = 0; i < 2; ++i) af[i] = *(const short8*)&As[wr + i * 16 + lr][ko];
#pragma unroll
      for (int i = 0; i < 2; ++i) bf[i] = *(const short8*)&Bs[wc + i * 16 + lr][ko];
#pragma unroll
      for (int mi = 0; mi < 2; ++mi)
#pragma unroll
        for (int ni = 0; ni < 2; ++ni)
          acc[mi][ni] = __builtin_amdgcn_mfma_f32_16x16x32_bf16(af[mi], bf[ni], acc[mi][ni], 0, 0, 0);
    }
    __syncthreads();
  }
#pragma unroll
  for (int mi = 0; mi < 2; ++mi) {
    const int row = m0 + wr + mi * 16 + (lane >> 4) * 4;
#pragma unroll
    for (int ni = 0; ni < 2; ++ni) {
      const int col = n0 + wc + ni * 16 + lr;
#pragma unroll
      for (int q = 0; q < 4; ++q)
        C[(size_t)(row + q) * N + col] = f2bf(acc[mi][ni][q]);
    }
  }
}

// ======== conv: 256x256 tile, 8-phase schedule, quarter-aligned race-free staging ========
// out[32768][512] = im2col(xbp)[32768][1152] @ wT[512][1152]^T + bias
#define MF(a_, b_, c_) __builtin_amdgcn_mfma_f32_16x16x32_bf16(a_, b_, c_, 0, 0, 0)

#define RD_A(bu_, mf_, ks_) \
  (*(const short8*)&As[bu_][wr * 128 + (mf_) * 16 + lr][(((ks_) * 4 + lh) ^ (lr & 7)) * 8])
#define RD_B(bu_, nf_, ks_) \
  (*(const short8*)&Bs[bu_][wc * 64 + (nf_) * 16 + lr][(((ks_) * 4 + lh) ^ (lr & 7)) * 8])

#define LOADB4(bu_) do { \
  bfr[0][0] = RD_B(bu_, 0, 0); bfr[0][1] = RD_B(bu_, 0, 1); \
  bfr[1][0] = RD_B(bu_, 1, 0); bfr[1][1] = RD_B(bu_, 1, 1); \
  bfr[2][0] = RD_B(bu_, 2, 0); bfr[2][1] = RD_B(bu_, 2, 1); \
  bfr[3][0] = RD_B(bu_, 3, 0); bfr[3][1] = RD_B(bu_, 3, 1); } while (0)

// stage quarter q of K-tile tt: A rows {wrB+32q..+31} per wave-group, 1 g2l16/thread
#define STAGE_AQ(q_, tt_) do { \
  const int tc_ = (tt_) > 17 ? 17 : (tt_); \
  const int khw_ = tc_ >> 1; const int kh_ = (khw_ * 11) >> 5; const int kw_ = khw_ - kh_ * 3; \
  const int ao_ = (kh_ * 34 + kw_) * 128 + ((tc_ & 1) << 6) + (q_) * 4352; \
  g2l16(xbp + aBase + ao_, &As[tc_ & 1][aRow + (q_) * 32][0]); } while (0)

#define STAGE_BQ(q_, tt_) do { \
  const int tc_ = (tt_) > 17 ? 17 : (tt_); \
  g2l16(wT + bBase + (q_) * 73728 + tc_ * 64, &Bs[tc_ & 1][bRow + (q_) * 64][0]); } while (0)

#define MFMA16(p_) \
  acc[2*(p_)  ][0] = MF(a0k0, bfr[0][0], acc[2*(p_)  ][0]); \
  acc[2*(p_)  ][1] = MF(a0k0, bfr[1][0], acc[2*(p_)  ][1]); \
  acc[2*(p_)  ][2] = MF(a0k0, bfr[2][0], acc[2*(p_)  ][2]); \
  acc[2*(p_)  ][3] = MF(a0k0, bfr[3][0], acc[2*(p_)  ][3]); \
  acc[2*(p_)+1][0] = MF(a1k0, bfr[0][0], acc[2*(p_)+1][0]); \
  acc[2*(p_)+1][1] = MF(a1k0, bfr[1][0], acc[2*(p_)+1][1]); \
  acc[2*(p_)+1][2] = MF(a1k0, bfr[2][0], acc[2*(p_)+1][2]); \
  acc[2*(p_)+1][3] = MF(a1k0, bfr[3][0], acc[2*(p_)+1][3]); \
  acc[2*(p_)  ][0] = MF(a0k1, bfr[0][1], acc[2*(p_)  ][0]); \
  acc[2*(p_)  ][1] = MF(a0k1, bfr[1][1], acc[2*(p_)  ][1]); \
  acc[2*(p_)  ][2] = MF(a0k1, bfr[2][1], acc[2*(p_)  ][2]); \
  acc[2*(p_)  ][3] = MF(a0k1, bfr[3][1], acc[2*(p_)  ][3]); \
  acc[2*(p_)+1][0] = MF(a1k1, bfr[0][1], acc[2*(p_)+1][0]); \
  acc[2*(p_)+1][1] = MF(a1k1, bfr[1][1], acc[2*(p_)+1][1]); \
  acc[2*(p_)+1][2] = MF(a1k1, bfr[2][1], acc[2*(p_)+1][2]); \
  acc[2*(p_)+1][3] = MF(a1k1, bfr[3][1], acc[2*(p_)+1][3]);

// phase p of a K-tile in buf bu: reads quarter p, then (post-barrier => race-free)
// stages quarter p of K-tile TT into buf[TT&1]
#define PHASE(bu_, p_, PRE, TT_, WAITV) do { \
  PRE; \
  short8 a0k0 = RD_A(bu_, 2*(p_), 0),   a0k1 = RD_A(bu_, 2*(p_), 1); \
  short8 a1k0 = RD_A(bu_, 2*(p_)+1, 0), a1k1 = RD_A(bu_, 2*(p_)+1, 1); \
  __builtin_amdgcn_s_barrier(); \
  asm volatile("s_waitcnt lgkmcnt(0)" ::: "memory"); \
  __builtin_amdgcn_sched_barrier(0); \
  STAGE_AQ(p_, TT_); \
  STAGE_BQ(p_, TT_); \
  __builtin_amdgcn_s_setprio(1); \
  MFMA16(p_) \
  __builtin_amdgcn_s_setprio(0); \
  WAITV; \
  __builtin_amdgcn_s_barrier(); \
} while (0)

#define VM8 asm volatile("s_waitcnt vmcnt(8)" ::: "memory")

__global__ __launch_bounds__(512, 2) void k_conv(const short* __restrict__ xbp,
                                                 const short* __restrict__ wT,
                                                 const float* __restrict__ bias,
                                                 float* __restrict__ out) {
  __shared__ __align__(16) short As[2][256][64];
  __shared__ __align__(16) short Bs[2][256][64];
  int bid = blockIdx.x;
  bid = (bid & 7) * 32 + (bid >> 3);           // bijective XCD swizzle (256 % 8 == 0)
  const int mt = bid >> 1, nt = bid & 1;
  const int m0 = mt << 8, n0 = nt << 8;
  const int tid = threadIdx.x;
  const int lane = tid & 63, wid = tid >> 6;   // 8 waves: 2M x 4N
  const int wr = wid >> 2, wc = wid & 3;
  const int lr = lane & 15, lh = lane >> 4;

  f32x4 acc[8][4] = {};
  short8 bfr[4][2];

  // staging geometry: 1 g2l16/thread covers 64 LDS rows (8 rows per wave)
  const int wrB = (wid >> 2) * 128;            // A half owned by this wave group
  const int rsub = (wid & 3) * 8 + (lane >> 3);// 0..31, row within 32-block
  const int sw = (lane & 7) ^ (lane >> 3);     // pre-swizzled 16B slot
  const int aRow = wrB + (wid & 3) * 8;        // wave-uniform LDS row base (A)
  const int bRow = wid * 8;                    // wave-uniform LDS row base (B)

  const int Mb = m0 + wrB + rsub;              // im2col row at q=0
  const int b = Mb >> 10, h0 = (Mb >> 5) & 31, w = Mb & 31;
  const unsigned aBase = (unsigned)((b * 34 + h0) * 34 + w) * 128 + sw * 8;
  const unsigned bBase = (unsigned)(n0 + wid * 8 + (lane >> 3)) * 1152 + sw * 8;

  // prologue: fully stage tiles 0 and 1 (8 quarter-ops each), wait tile 0
  STAGE_AQ(0, 0); STAGE_BQ(0, 0); STAGE_AQ(1, 0); STAGE_BQ(1, 0);
  STAGE_AQ(2, 0); STAGE_BQ(2, 0); STAGE_AQ(3, 0); STAGE_BQ(3, 0);
  STAGE_AQ(0, 1); STAGE_BQ(0, 1); STAGE_AQ(1, 1); STAGE_BQ(1, 1);
  STAGE_AQ(2, 1); STAGE_BQ(2, 1); STAGE_AQ(3, 1); STAGE_BQ(3, 1);
  VM8;
  __builtin_amdgcn_s_barrier();

  for (int it = 0; it < 9; ++it) {
    const int ta = 2 * it;
    PHASE(0, 0, LOADB4(0), ta + 2, );
    PHASE(0, 1, ,          ta + 2, );
    PHASE(0, 2, ,          ta + 2, );
    PHASE(0, 3, ,          ta + 2, VM8);
    PHASE(1, 0, LOADB4(1), ta + 3, );
    PHASE(1, 1, ,          ta + 3, );
    PHASE(1, 2, ,          ta + 3, );
    PHASE(1, 3, ,          ta + 3, VM8);
  }
  asm volatile("s_waitcnt vmcnt(0)" ::: "memory");

  // epilogue: fp32 + bias
  const int orow = m0 + wr * 128, ocol = n0 + wc * 64;
#pragma unroll
  for (int mf = 0; mf < 8; ++mf) {
    const int row = orow + mf * 16 + lh * 4;
#pragma unroll
    for (int nf = 0; nf < 4; ++nf) {
      const int col = ocol + nf * 16 + lr;
      const float bv = bias[col];
#pragma unroll
      for (int q = 0; q < 4; ++q)
        out[(size_t)(row + q) * 512 + col] = acc[mf][nf][q] + bv;
    }
  }
}

extern "C" void kernel_launch(void* const* d_in, const int* in_sizes, int n_in,
                              void* d_out, int out_size, void* d_ws, size_t ws_size,
                              hipStream_t stream) {
  (void)in_sizes; (void)n_in; (void)out_size; (void)ws_size;
  const float* x    = (const float*)d_in[0];
  const float* k0   = (const float*)d_in[1];
  const float* k1   = (const float*)d_in[2];
  const float* k2   = (const float*)d_in[3];
  const float* m0   = (const float*)d_in[4];
  const float* m1   = (const float*)d_in[5];
  const float* m2   = (const float*)d_in[6];
  const float* sc   = (const float*)d_in[7];
  const float* bias = (const float*)d_in[8];
  float* out = (float*)d_out;
  char* ws = (char*)d_ws;

  short* xbp = (short*)(ws);              // 32*34*34*128 bf16 = 9,469,952 B
  short* w1b = (short*)(ws + 9469952);    // 1152*1152 bf16    = 2,654,208 B
  short* w2T = (short*)(ws + 12124160);   // 512*1152 bf16     = 1,179,648 B
  short* w3T = (short*)(ws + 13303808);   // 512*512 bf16      =   524,288 B
  short* A1b = (short*)(ws + 13828096);   // 1152*512 bf16     = 1,179,648 B
  short* wET = (short*)(ws + 15007744);   // 512*1152 bf16     = 1,179,648 B

  k_prep<<<3792, 256, 0, stream>>>(x, k0, m0, sc, k1, m1, k2, m2, xbp, w1b, w2T, w3T);
  // A1 (1152x512) = w1 @ w2 ; A=w1b[1152][1152], BT=w2T[512][1152]
  k_gemm64<<<144, 256, 0, stream>>>(w1b, w2T, A1b, 1152, 512, 1152);
  // wEffT (512x1152) = w3T @ A1^T (== (A1@w3)^T) ; A=w3T[512][512], BT=A1b[1152][512]
  k_gemm64<<<144, 256, 0, stream>>>(w3T, A1b, wET, 512, 1152, 512);
  k_conv<<<256, 512, 0, stream>>>(xbp, wET, bias, out);
}

// Round 5
// 76.173 us; speedup vs baseline: 1.8355x; 1.0425x over previous
//
#include <hip/hip_runtime.h>

typedef __attribute__((ext_vector_type(8))) short short8;
typedef __attribute__((ext_vector_type(4))) float f32x4;

typedef __attribute__((address_space(1))) const unsigned gas_u32;
typedef __attribute__((address_space(3))) unsigned las_u32;

static __device__ __forceinline__ void g2l16(const void* g, void* l) {
  __builtin_amdgcn_global_load_lds((gas_u32*)g, (las_u32*)l, 16, 0, 0);
}

static __device__ __forceinline__ short f2bf(float f) {
  union { float f; unsigned u; } v; v.f = f;
  unsigned r = (v.u + 0x7FFFu + ((v.u >> 16) & 1u)) >> 16;   // RNE
  return (short)r;
}

// ---- fused prep: maskmul | tmask(k1,m1) | tmask(k2,m2) | cvt_pad ----
__global__ __launch_bounds__(256) void k_prep(const float* __restrict__ x,
                                              const float* __restrict__ k0f,
                                              const float* __restrict__ m0f,
                                              const float* __restrict__ scf,
                                              const float* __restrict__ k1f,
                                              const float* __restrict__ m1f,
                                              const float* __restrict__ k2f,
                                              const float* __restrict__ m2f,
                                              short* __restrict__ xbp,
                                              short* __restrict__ w1b,
                                              short* __restrict__ w2T,
                                              short* __restrict__ w3T) {
  __shared__ float tile[32][33];
  const int bb = blockIdx.x, tid = threadIdx.x;
  if (bb < 648) {
    int i = bb * 256 + tid;
    float s = scf[0];
    const f32x4* kk = (const f32x4*)k0f + (size_t)i * 2;
    const f32x4* mm = (const f32x4*)m0f + (size_t)i * 2;
    f32x4 a0 = kk[0], a1 = kk[1], b0 = mm[0], b1 = mm[1];
    short8 o;
    o[0] = f2bf(a0[0] * b0[0] * s); o[1] = f2bf(a0[1] * b0[1] * s);
    o[2] = f2bf(a0[2] * b0[2] * s); o[3] = f2bf(a0[3] * b0[3] * s);
    o[4] = f2bf(a1[0] * b1[0] * s); o[5] = f2bf(a1[1] * b1[1] * s);
    o[6] = f2bf(a1[2] * b1[2] * s); o[7] = f2bf(a1[3] * b1[3] * s);
    ((short8*)w1b)[i] = o;
  } else if (bb < 1480) {
    const float *kf, *mf; short* outp; int D, F, idx;
    if (bb < 1224) { kf = k1f; mf = m1f; outp = w2T; D = 1152; F = 512; idx = bb - 648; }
    else           { kf = k2f; mf = m2f; outp = w3T; D = 512;  F = 512; idx = bb - 1224; }
    int f0 = (idx & 15) * 32, d0 = (idx >> 4) * 32;
    int tx = tid & 31, ty = tid >> 5;
#pragma unroll
    for (int i = 0; i < 4; ++i) {
      int d = d0 + ty + i * 8;
      size_t ix = (size_t)d * F + f0 + tx;
      tile[ty + i * 8][tx] = kf[ix] * mf[ix];
    }
    __syncthreads();
#pragma unroll
    for (int i = 0; i < 4; ++i) {
      int f = f0 + ty + i * 8;
      outp[(size_t)f * D + d0 + tx] = f2bf(tile[tx][ty + i * 8]);
    }
  } else {
    int i = (bb - 1480) * 256 + tid;
    int c8 = i & 15;
    int t = i >> 4;
    int wp = t % 34, t2 = t / 34;
    int hp = t2 % 34, b = t2 / 34;
    short8 o = {};
    if (hp >= 1 && hp <= 32 && wp >= 1 && wp <= 32) {
      const f32x4* s = (const f32x4*)(x + (((size_t)((b << 5) + hp - 1) << 5) + (wp - 1)) * 128 + c8 * 8);
      f32x4 a = s[0], bb2 = s[1];
      o[0] = f2bf(a[0]); o[1] = f2bf(a[1]); o[2] = f2bf(a[2]); o[3] = f2bf(a[3]);
      o[4] = f2bf(bb2[0]); o[5] = f2bf(bb2[1]); o[6] = f2bf(bb2[2]); o[7] = f2bf(bb2[3]);
    }
    ((short8*)xbp)[i] = o;
  }
}

// ---- bf16 GEMM 64x64 tiles: C[M][N] = A[M][K] @ BT[N][K]^T  (gload_lds staging) ----
__global__ __launch_bounds__(256) void k_gemm64(const short* __restrict__ A,
                                                const short* __restrict__ BT,
                                                short* __restrict__ C, int M, int N, int K) {
  __shared__ __align__(16) short As[64][64];
  __shared__ __align__(16) short Bs[64][64];
  const int ntiles = N >> 6;
  const int m0 = (blockIdx.x / ntiles) << 6, n0 = (blockIdx.x % ntiles) << 6;
  const int tid = threadIdx.x;
  const int lane = tid & 63, wv = tid >> 6;
  const int wr = (wv >> 1) * 32, wc = (wv & 1) * 32;
  const int lr = lane & 15, lk = (lane >> 4) * 8;

  f32x4 acc[2][2] = {};

  const int rr = tid >> 3, c8 = (tid & 7) * 8;
  unsigned abase[2], bbase[2];
#pragma unroll
  for (int j = 0; j < 2; ++j) {
    abase[j] = (unsigned)(m0 + j * 32 + rr) * K + c8;
    bbase[j] = (unsigned)(n0 + j * 32 + rr) * K + c8;
  }
  short* AsL = &As[0][0];
  short* BsL = &Bs[0][0];
  const int lo = wv * 512;

  for (int kt = 0; kt < K; kt += 64) {
#pragma unroll
    for (int j = 0; j < 2; ++j) g2l16(A + abase[j] + kt, AsL + j * 2048 + lo);
#pragma unroll
    for (int j = 0; j < 2; ++j) g2l16(BT + bbase[j] + kt, BsL + j * 2048 + lo);
    __syncthreads();
#pragma unroll
    for (int ks = 0; ks < 2; ++ks) {
      const int ko = ks * 32 + lk;
      short8 af[2], bf[2];
#pragma unroll
      for (int i = 0; i < 2; ++i) af[i] = *(const short8*)&As[wr + i * 16 + lr][ko];
#pragma unroll
      for (int i = 0; i < 2; ++i) bf[i] = *(const short8*)&Bs[wc + i * 16 + lr][ko];
#pragma unroll
      for (int mi = 0; mi < 2; ++mi)
#pragma unroll
        for (int ni = 0; ni < 2; ++ni)
          acc[mi][ni] = __builtin_amdgcn_mfma_f32_16x16x32_bf16(af[mi], bf[ni], acc[mi][ni], 0, 0, 0);
    }
    __syncthreads();
  }
#pragma unroll
  for (int mi = 0; mi < 2; ++mi) {
    const int row = m0 + wr + mi * 16 + (lane >> 4) * 4;
#pragma unroll
    for (int ni = 0; ni < 2; ++ni) {
      const int col = n0 + wc + ni * 16 + lr;
#pragma unroll
      for (int q = 0; q < 4; ++q)
        C[(size_t)(row + q) * N + col] = f2bf(acc[mi][ni][q]);
    }
  }
}

// ======== conv: 256x128 tile, single-buffer BK=64, 4-phase, 2 blocks/CU ========
// out[32768][512] = im2col(xbp)[32768][1152] @ wT[512][1152]^T + bias
#define MF(a_, b_, c_) __builtin_amdgcn_mfma_f32_16x16x32_bf16(a_, b_, c_, 0, 0, 0)

#define RD_A(mf_, ks_) \
  (*(const short8*)&As[wr * 128 + (mf_) * 16 + lr][(((ks_) * 4 + lh) ^ (lr & 7)) * 8])
#define RD_B(nf_, ks_) \
  (*(const short8*)&Bs[wc * 32 + (nf_) * 16 + lr][(((ks_) * 4 + lh) ^ (lr & 7)) * 8])

#define LOADB do { \
  bfr[0][0] = RD_B(0, 0); bfr[0][1] = RD_B(0, 1); \
  bfr[1][0] = RD_B(1, 0); bfr[1][1] = RD_B(1, 1); } while (0)

// stage A quarter q of K-tile tt (64 LDS rows: {32q..+31} in each 128-half), 1 op/thread
#define STAGE_AQ(q_, tt_) do { \
  const int tc_ = (tt_) > 17 ? 17 : (tt_); \
  const int khw_ = tc_ >> 1; const int kh_ = (khw_ * 11) >> 5; const int kw_ = khw_ - kh_ * 3; \
  const int ao_ = (kh_ * 34 + kw_) * 128 + ((tc_ & 1) << 6) + (q_) * 4352; \
  g2l16(xbp + aBase + ao_, &As[aRow + (q_) * 32][0]); } while (0)

// stage B half j (64 rows) of K-tile tt, 1 op/thread
#define STAGE_BH(j_, tt_) do { \
  const int tc_ = (tt_) > 17 ? 17 : (tt_); \
  g2l16(wT + bBase + (j_) * 73728 + tc_ * 64, &Bs[(j_) * 64 + bRow][0]); } while (0)

#define MFMA8(p_) \
  acc[2*(p_)  ][0] = MF(a0k0, bfr[0][0], acc[2*(p_)  ][0]); \
  acc[2*(p_)  ][1] = MF(a0k0, bfr[1][0], acc[2*(p_)  ][1]); \
  acc[2*(p_)+1][0] = MF(a1k0, bfr[0][0], acc[2*(p_)+1][0]); \
  acc[2*(p_)+1][1] = MF(a1k0, bfr[1][0], acc[2*(p_)+1][1]); \
  acc[2*(p_)  ][0] = MF(a0k1, bfr[0][1], acc[2*(p_)  ][0]); \
  acc[2*(p_)  ][1] = MF(a0k1, bfr[1][1], acc[2*(p_)  ][1]); \
  acc[2*(p_)+1][0] = MF(a1k1, bfr[0][1], acc[2*(p_)+1][0]); \
  acc[2*(p_)+1][1] = MF(a1k1, bfr[1][1], acc[2*(p_)+1][1]);

// phase p: read quarter p of current tile (pre-barrier), then post-barrier stage
// the same quarter of the NEXT tile (write-after-read safe), MFMA, counted wait.
#define PHASE(p_, PRE, WAITV, ...) do { \
  PRE; \
  short8 a0k0 = RD_A(2*(p_), 0),   a0k1 = RD_A(2*(p_), 1); \
  short8 a1k0 = RD_A(2*(p_)+1, 0), a1k1 = RD_A(2*(p_)+1, 1); \
  __builtin_amdgcn_s_barrier(); \
  asm volatile("s_waitcnt lgkmcnt(0)" ::: "memory"); \
  __builtin_amdgcn_sched_barrier(0); \
  __VA_ARGS__ \
  __builtin_amdgcn_s_setprio(1); \
  MFMA8(p_) \
  __builtin_amdgcn_s_setprio(0); \
  WAITV; \
  __builtin_amdgcn_s_barrier(); \
} while (0)

#define VM5 asm volatile("s_waitcnt vmcnt(5)" ::: "memory")
#define VM3 asm volatile("s_waitcnt vmcnt(3)" ::: "memory")

__global__ __launch_bounds__(512, 4) void k_conv(const short* __restrict__ xbp,
                                                 const short* __restrict__ wT,
                                                 const float* __restrict__ bias,
                                                 float* __restrict__ out) {
  __shared__ __align__(16) short As[256][64];   // 32 KiB
  __shared__ __align__(16) short Bs[128][64];   // 16 KiB
  int bid = blockIdx.x;
  bid = (bid & 7) * 64 + (bid >> 3);            // bijective XCD swizzle (512 % 8 == 0)
  const int mt = bid >> 2, nt = bid & 3;
  const int m0 = mt << 8, n0 = nt << 7;
  const int tid = threadIdx.x;
  const int lane = tid & 63, wid = tid >> 6;    // 8 waves: 2M x 4N
  const int wr = wid >> 2, wc = wid & 3;
  const int lr = lane & 15, lh = lane >> 4;

  f32x4 acc[8][2] = {};
  short8 bfr[2][2];

  // staging geometry (1 g2l16/thread covers 64 LDS rows; 8 rows/wave)
  const int wrB = (wid >> 2) * 128;
  const int rsub = (wid & 3) * 8 + (lane >> 3); // 0..31
  const int sw = (lane & 7) ^ (lane >> 3);      // pre-swizzled 16B slot
  const int aRow = wrB + (wid & 3) * 8;         // wave-uniform LDS row base (A)
  const int bRow = wid * 8;                     // wave-uniform LDS row base (B)

  const int Mb = m0 + wrB + rsub;
  const int b = Mb >> 10, h0 = (Mb >> 5) & 31, w = Mb & 31;
  const unsigned aBase = (unsigned)((b * 34 + h0) * 34 + w) * 128 + sw * 8;
  const unsigned bBase = (unsigned)(n0 + wid * 8 + (lane >> 3)) * 1152 + sw * 8;

  // prologue: stage tile 0 fully (6 ops/thread), drain, barrier
  STAGE_BH(0, 0); STAGE_BH(1, 0);
  STAGE_AQ(0, 0); STAGE_AQ(1, 0); STAGE_AQ(2, 0); STAGE_AQ(3, 0);
  asm volatile("s_waitcnt vmcnt(0)" ::: "memory");
  __builtin_amdgcn_s_barrier();

  for (int t = 0; t < 18; ++t) {
    const int tn = t + 1;  // clamped inside STAGE macros (idempotent restage at tail)
    PHASE(0, LOADB, VM5, STAGE_BH(0, tn); STAGE_BH(1, tn); STAGE_AQ(0, tn););
    PHASE(1, ,      VM5, STAGE_AQ(1, tn););
    PHASE(2, ,      VM5, STAGE_AQ(2, tn););
    PHASE(3, ,      VM3, STAGE_AQ(3, tn););
  }
  asm volatile("s_waitcnt vmcnt(0)" ::: "memory");

  // epilogue: fp32 + bias
  const int orow = m0 + wr * 128, ocol = n0 + wc * 32;
#pragma unroll
  for (int mf = 0; mf < 8; ++mf) {
    const int row = orow + mf * 16 + lh * 4;
#pragma unroll
    for (int nf = 0; nf < 2; ++nf) {
      const int col = ocol + nf * 16 + lr;
      const float bv = bias[col];
#pragma unroll
      for (int q = 0; q < 4; ++q)
        out[(size_t)(row + q) * 512 + col] = acc[mf][nf][q] + bv;
    }
  }
}

extern "C" void kernel_launch(void* const* d_in, const int* in_sizes, int n_in,
                              void* d_out, int out_size, void* d_ws, size_t ws_size,
                              hipStream_t stream) {
  (void)in_sizes; (void)n_in; (void)out_size; (void)ws_size;
  const float* x    = (const float*)d_in[0];
  const float* k0   = (const float*)d_in[1];
  const float* k1   = (const float*)d_in[2];
  const float* k2   = (const float*)d_in[3];
  const float* m0   = (const float*)d_in[4];
  const float* m1   = (const float*)d_in[5];
  const float* m2   = (const float*)d_in[6];
  const float* sc   = (const float*)d_in[7];
  const float* bias = (const float*)d_in[8];
  float* out = (float*)d_out;
  char* ws = (char*)d_ws;

  short* xbp = (short*)(ws);              // 32*34*34*128 bf16 = 9,469,952 B
  short* w1b = (short*)(ws + 9469952);    // 1152*1152 bf16    = 2,654,208 B
  short* w2T = (short*)(ws + 12124160);   // 512*1152 bf16     = 1,179,648 B
  short* w3T = (short*)(ws + 13303808);   // 512*512 bf16      =   524,288 B
  short* A1b = (short*)(ws + 13828096);   // 1152*512 bf16     = 1,179,648 B
  short* wET = (short*)(ws + 15007744);   // 512*1152 bf16     = 1,179,648 B

  k_prep<<<3792, 256, 0, stream>>>(x, k0, m0, sc, k1, m1, k2, m2, xbp, w1b, w2T, w3T);
  // A1 (1152x512) = w1 @ w2 ; A=w1b[1152][1152], BT=w2T[512][1152]
  k_gemm64<<<144, 256, 0, stream>>>(w1b, w2T, A1b, 1152, 512, 1152);
  // wEffT (512x1152) = w3T @ A1^T (== (A1@w3)^T) ; A=w3T[512][512], BT=A1b[1152][512]
  k_gemm64<<<144, 256, 0, stream>>>(w3T, A1b, wET, 512, 1152, 512);
  k_conv<<<512, 512, 0, stream>>>(xbp, wET, bias, out);
}